// Round 13
// baseline (1163.236 us; speedup 1.0000x reference)
//
#include <hip/hip_runtime.h>
#include <hip/hip_fp16.h>
#include <math.h>

#define N_NODES 102400
#define N_EDGES 1638400
#define NB 100            // coarse buckets: node range 1024
#define PB 256            // partition blocks (= mega_build grid)
#define EPB (N_EDGES/PB)  // 6400 edges per partition block
#define AGG_BLOCKS 1536   // mega_agg grid: 6 blocks/CU on 256 CUs
#define AGG_WAVES (AGG_BLOCKS*4)

union H4 { int2 i2; __half h[4]; };

// ---- software grid barrier (all blocks resident by construction) ----
__device__ __forceinline__ void grid_sync(int* bar, int idx, int nblocks) {
    __syncthreads();
    if (threadIdx.x == 0) {
        __threadfence();  // release: drain writes device-scope
        __hip_atomic_fetch_add(&bar[idx], 1, __ATOMIC_RELEASE, __HIP_MEMORY_SCOPE_AGENT);
        while (__hip_atomic_load(&bar[idx], __ATOMIC_ACQUIRE, __HIP_MEMORY_SCOPE_AGENT) < nblocks)
            __builtin_amdgcn_s_sleep(2);
        __threadfence();  // acquire: invalidate caches before consuming
    }
    __syncthreads();
}

// =================== mega_build: histA -> scanB -> partC -> fineS -> fineD ===================
__global__ __launch_bounds__(256) void mega_build_kernel(
    const int* __restrict__ src, const int* __restrict__ dst, const float* __restrict__ ew,
    int* __restrict__ histD, int* __restrict__ histS,
    int* __restrict__ offD, int* __restrict__ offS,
    int* __restrict__ coarseD, int* __restrict__ coarseS,
    int2* __restrict__ partD, int* __restrict__ partS,
    int2* __restrict__ edge_perm, int* __restrict__ row_off,
    float* __restrict__ outdeg_inv, float* __restrict__ indeg_inv,
    int* __restrict__ bar) {
    __shared__ int hD[NB], hS[NB];          // P1 hist / P3 cursors (reused)
    __shared__ int hist_f[1024];            // P4 src-fine hist / P5 dst-fine hist (reused)
    __shared__ int cur_f[1024];             // P5 cursors
    __shared__ int wsum[4];
    const int tid = threadIdx.x;
    const int bid = blockIdx.x;
    const int lane = tid & 63, wid = tid >> 6;

    // ---- P1: coarse histograms ----
    if (tid < NB) { hD[tid] = 0; hS[tid] = 0; }
    __syncthreads();
    {
        int base = bid * EPB;
        for (int i = tid; i < EPB; i += 256) {
            atomicAdd(&hD[dst[base + i] >> 10], 1);
            atomicAdd(&hS[src[base + i] >> 10], 1);
        }
    }
    __syncthreads();
    if (tid < NB) {
        histD[bid * NB + tid] = hD[tid];
        histS[bid * NB + tid] = hS[tid];
    }
    grid_sync(bar, 0, PB);

    // ---- P2: scan block-bucket matrices (block 0 only) ----
    if (bid == 0) {
        __shared__ int totD[NB], totS[NB], baseD[NB + 1], baseS[NB + 1];
        int t = tid;
        if (t < NB) { int s = 0; for (int k = 0; k < PB; k++) s += histD[k * NB + t]; totD[t] = s; }
        else if (t >= 128 && t < 128 + NB) { int j = t - 128; int s = 0; for (int k = 0; k < PB; k++) s += histS[k * NB + j]; totS[j] = s; }
        __syncthreads();
        if (t == 0)   { int r = 0; for (int j = 0; j < NB; j++) { baseD[j] = r; r += totD[j]; } baseD[NB] = r; }
        if (t == 128) { int r = 0; for (int j = 0; j < NB; j++) { baseS[j] = r; r += totS[j]; } baseS[NB] = r; }
        __syncthreads();
        if (t < NB) { int r = baseD[t]; for (int k = 0; k < PB; k++) { offD[k * NB + t] = r; r += histD[k * NB + t]; } }
        else if (t >= 128 && t < 128 + NB) { int j = t - 128; int r = baseS[j]; for (int k = 0; k < PB; k++) { offS[k * NB + j] = r; r += histS[k * NB + j]; } }
        if (t <= NB) coarseD[t] = baseD[t];
        if (t >= 128 && t <= 128 + NB) coarseS[t - 128] = baseS[t - 128];
    }
    grid_sync(bar, 1, PB);

    // ---- P3: partition edges into coarse buckets (LDS cursors) ----
    if (tid < NB) { hD[tid] = offD[bid * NB + tid]; hS[tid] = offS[bid * NB + tid]; }
    __syncthreads();
    {
        int base = bid * EPB;
        for (int i = tid; i < EPB; i += 256) {
            int s = src[base + i], d = dst[base + i];
            float w = ew[base + i];
            int p = atomicAdd(&hD[d >> 10], 1);
            partD[p] = make_int2(s | ((d & 1023) << 17), __float_as_int(w));
            int q = atomicAdd(&hS[s >> 10], 1);
            partS[q] = s & 1023;
        }
    }
    grid_sync(bar, 2, PB);

    // ---- P4: per src-bucket fine hist -> outdeg_inv (blocks 0..99) ----
    if (bid < NB) {
        #pragma unroll
        for (int j = 0; j < 4; ++j) hist_f[tid + j * 256] = 0;
        __syncthreads();
        int beg = coarseS[bid], end = coarseS[bid + 1];
        for (int i = beg + tid; i < end; i += 256) atomicAdd(&hist_f[partS[i]], 1);
        __syncthreads();
        int4 h = *(const int4*)&hist_f[tid * 4];
        float4 o;
        o.x = 1.0f / sqrtf((float)max(h.x, 1));
        o.y = 1.0f / sqrtf((float)max(h.y, 1));
        o.z = 1.0f / sqrtf((float)max(h.z, 1));
        o.w = 1.0f / sqrtf((float)max(h.w, 1));
        *(float4*)(outdeg_inv + bid * 1024 + tid * 4) = o;
    }
    grid_sync(bar, 3, PB);

    // ---- P5: per dst-bucket fine sort -> row_off, indeg_inv, edge_perm (blocks 0..99) ----
    if (bid < NB) {
        #pragma unroll
        for (int j = 0; j < 4; ++j) hist_f[tid + j * 256] = 0;
        __syncthreads();
        int beg = coarseD[bid], end = coarseD[bid + 1];
        for (int i = beg + tid; i < end; i += 256) atomicAdd(&hist_f[(partD[i].x >> 17) & 1023], 1);
        __syncthreads();
        int4 h = *(const int4*)&hist_f[tid * 4];
        int v = h.x + h.y + h.z + h.w;
        // block scan of per-thread totals (4 waves)
        int x = v;
        #pragma unroll
        for (int s = 1; s < 64; s <<= 1) { int t = __shfl_up(x, s, 64); if (lane >= s) x += t; }
        if (lane == 63) wsum[wid] = x;
        __syncthreads();
        if (tid == 0) { int r = 0; for (int j = 0; j < 4; ++j) { int t = wsum[j]; wsum[j] = r; r += t; } }
        __syncthreads();
        int s0 = beg + wsum[wid] + x - v;
        int s1 = s0 + h.x, s2 = s1 + h.y, s3 = s2 + h.z;
        int node = bid * 1024 + tid * 4;
        *(int4*)(row_off + node) = make_int4(s0, s1, s2, s3);
        float4 ii;
        ii.x = 1.0f / sqrtf((float)max(h.x, 1));
        ii.y = 1.0f / sqrtf((float)max(h.y, 1));
        ii.z = 1.0f / sqrtf((float)max(h.z, 1));
        ii.w = 1.0f / sqrtf((float)max(h.w, 1));
        *(float4*)(indeg_inv + node) = ii;
        *(int4*)&cur_f[tid * 4] = make_int4(s0, s1, s2, s3);
        if (bid == NB - 1 && tid == 0) row_off[N_NODES] = N_EDGES;
        __syncthreads();
        for (int i = beg + tid; i < end; i += 256) {
            int2 t2 = partD[i];
            int d = (t2.x >> 17) & 1023, s = t2.x & 0x1FFFF;
            int p = atomicAdd(&cur_f[d], 1);
            float w = __int_as_float(t2.y) * outdeg_inv[s];
            edge_perm[p] = make_int2(s, __float_as_int(w));
        }
    }
}

// =================== gemm0: out(fp16) = h @ W0, register-tiled ===================
template<int K, int C, int RN>
__global__ __launch_bounds__(256) void gemm_tile_kernel(
    const float* __restrict__ h, const float* __restrict__ W, __half* __restrict__ out) {
    constexpr int BM = 64;
    constexpr int RM = 4;
    constexpr int KC = 64;
    constexpr int TX = C / RN;
    constexpr int TY = BM / RM;
    static_assert(TX * TY == 256, "bad tile");
    static_assert(RN == 4, "fp16 epilogue assumes RN==4");

    __shared__ float Ws[K * C];
    __shared__ float Hs[KC][BM + 4];

    const int tid = threadIdx.x;
    const long brow = (long)blockIdx.x * BM;

    for (int i = tid; i < K * C; i += 256) Ws[i] = W[i];

    const int tx = tid % TX;
    const int ty = tid / TX;
    float acc[RM][RN] = {};

    const int lr = tid % 16;
    const int lk = tid / 16;

    for (int kc = 0; kc < K; kc += KC) {
        __syncthreads();
        #pragma unroll
        for (int p0 = 0; p0 < BM; p0 += 16) {
            const int r = p0 + lr;
            const float4 hv = *(const float4*)(h + (brow + r) * K + kc + lk * 4);
            Hs[lk * 4 + 0][r] = hv.x;
            Hs[lk * 4 + 1][r] = hv.y;
            Hs[lk * 4 + 2][r] = hv.z;
            Hs[lk * 4 + 3][r] = hv.w;
        }
        __syncthreads();

        #pragma unroll
        for (int k = 0; k < KC; ++k) {
            const float4 a4 = *(const float4*)&Hs[k][ty * RM];
            const float av[RM] = {a4.x, a4.y, a4.z, a4.w};
            float b[RN];
            *(float4*)b = *(const float4*)&Ws[(kc + k) * C + tx * RN];
            #pragma unroll
            for (int i = 0; i < RM; ++i)
                #pragma unroll
                for (int j = 0; j < RN; ++j)
                    acc[i][j] += av[i] * b[j];
        }
    }

    #pragma unroll
    for (int i = 0; i < RM; ++i) {
        const long row = brow + ty * RM + i;
        __half2 p01 = __floats2half2_rn(acc[i][0], acc[i][1]);
        __half2 p23 = __floats2half2_rn(acc[i][2], acc[i][3]);
        int2 packed = make_int2(*(int*)&p01, *(int*)&p23);
        *(int2*)(out + row * C + tx * RN) = packed;
    }
}

// =================== mega_agg: agg64+gemm -> agg32+dot -> agg1, persistent ===================
__global__ __launch_bounds__(256, 6) void mega_agg_kernel(
    const __half* __restrict__ ht, const int* __restrict__ row_off,
    const int2* __restrict__ ep, const float* __restrict__ indeg_inv,
    const float* __restrict__ b0, const float* __restrict__ W1,
    __half* __restrict__ ht1,
    const float* __restrict__ b1, const float* __restrict__ W2, float* __restrict__ ht2,
    const float* __restrict__ b2, float* __restrict__ out,
    int* __restrict__ bar) {
    __shared__ float W1s[64 * 32];
    __shared__ float h1s[4][64];
    const int tid = threadIdx.x;
    {   // vectorized W1 staging
        const float4* W1v = (const float4*)W1;
        float4* W1sv = (float4*)W1s;
        W1sv[tid] = W1v[tid];
        W1sv[tid + 256] = W1v[tid + 256];
    }
    __syncthreads();

    const int lane = tid & 63;
    const int wv = tid >> 6;
    const int w = blockIdx.x * 4 + wv;   // global wave id, 0..AGG_WAVES-1

    // ---- A1: layer-0 aggregation (fp16 gather) + fused 64->32 transform ----
    {
        int chunk = lane & 15;
        int eslot = lane >> 4;
        const char* htb = (const char*)ht;
        unsigned coff = (unsigned)(chunk << 3);
        int c = lane & 31, half = lane >> 5;
        for (int node = w; node < N_NODES; node += AGG_WAVES) {
            int beg = row_off[node], end = row_off[node + 1];
            float4 a0 = {0, 0, 0, 0}, a1 = {0, 0, 0, 0};
            for (int e = beg; e < end; e += 8) {
                int ei0 = e + eslot, ei1 = e + 4 + eslot;
                int2 d0 = ep[min(ei0, end - 1)];
                int2 d1 = ep[min(ei1, end - 1)];
                float w0 = (ei0 < end) ? __int_as_float(d0.y) : 0.0f;
                float w1 = (ei1 < end) ? __int_as_float(d1.y) : 0.0f;
                H4 r0, r1;
                r0.i2 = *(const int2*)(htb + (((unsigned)d0.x << 7) | coff));
                r1.i2 = *(const int2*)(htb + (((unsigned)d1.x << 7) | coff));
                a0.x = fmaf(__half2float(r0.h[0]), w0, a0.x);
                a0.y = fmaf(__half2float(r0.h[1]), w0, a0.y);
                a0.z = fmaf(__half2float(r0.h[2]), w0, a0.z);
                a0.w = fmaf(__half2float(r0.h[3]), w0, a0.w);
                a1.x = fmaf(__half2float(r1.h[0]), w1, a1.x);
                a1.y = fmaf(__half2float(r1.h[1]), w1, a1.y);
                a1.z = fmaf(__half2float(r1.h[2]), w1, a1.z);
                a1.w = fmaf(__half2float(r1.h[3]), w1, a1.w);
            }
            a0.x += a1.x; a0.y += a1.y; a0.z += a1.z; a0.w += a1.w;
            #pragma unroll
            for (int s = 16; s <= 32; s <<= 1) {
                a0.x += __shfl_xor(a0.x, s, 64);
                a0.y += __shfl_xor(a0.y, s, 64);
                a0.z += __shfl_xor(a0.z, s, 64);
                a0.w += __shfl_xor(a0.w, s, 64);
            }
            if (eslot == 0) {
                float sc = indeg_inv[node];
                float4 b = *(const float4*)(b0 + chunk * 4);
                float4 v;
                v.x = tanhf(a0.x * sc + b.x);
                v.y = tanhf(a0.y * sc + b.y);
                v.z = tanhf(a0.z * sc + b.z);
                v.w = tanhf(a0.w * sc + b.w);
                *(float4*)&h1s[wv][chunk * 4] = v;
            }
            float t = 0.0f;
            #pragma unroll
            for (int j4 = 0; j4 < 8; ++j4) {
                int k = half * 32 + j4 * 4;
                float4 hh = *(const float4*)&h1s[wv][k];
                t += hh.x * W1s[(k + 0) * 32 + c];
                t += hh.y * W1s[(k + 1) * 32 + c];
                t += hh.z * W1s[(k + 2) * 32 + c];
                t += hh.w * W1s[(k + 3) * 32 + c];
            }
            t += __shfl_xor(t, 32, 64);
            if (half == 0) ht1[(long)node * 32 + c] = __float2half_rn(t);
        }
    }
    grid_sync(bar + 4, 0, AGG_BLOCKS);

    // ---- A2: layer-1 aggregation (fp16 gather) + fused 32->1 dot ----
    {
        int chunk = lane & 7;
        int eslot = lane >> 3;
        const char* htb = (const char*)ht1;
        unsigned coff = (unsigned)(chunk << 3);
        float4 b = *(const float4*)(b1 + chunk * 4);
        float4 w2 = *(const float4*)(W2 + chunk * 4);
        for (int node = w; node < N_NODES; node += AGG_WAVES) {
            int beg = row_off[node], end = row_off[node + 1];
            float4 a0 = {0, 0, 0, 0}, a1 = {0, 0, 0, 0};
            for (int e = beg; e < end; e += 16) {
                int ei0 = e + eslot, ei1 = e + 8 + eslot;
                int2 d0 = ep[min(ei0, end - 1)];
                int2 d1 = ep[min(ei1, end - 1)];
                float w0 = (ei0 < end) ? __int_as_float(d0.y) : 0.0f;
                float w1 = (ei1 < end) ? __int_as_float(d1.y) : 0.0f;
                H4 r0, r1;
                r0.i2 = *(const int2*)(htb + (((unsigned)d0.x << 6) | coff));
                r1.i2 = *(const int2*)(htb + (((unsigned)d1.x << 6) | coff));
                a0.x = fmaf(__half2float(r0.h[0]), w0, a0.x);
                a0.y = fmaf(__half2float(r0.h[1]), w0, a0.y);
                a0.z = fmaf(__half2float(r0.h[2]), w0, a0.z);
                a0.w = fmaf(__half2float(r0.h[3]), w0, a0.w);
                a1.x = fmaf(__half2float(r1.h[0]), w1, a1.x);
                a1.y = fmaf(__half2float(r1.h[1]), w1, a1.y);
                a1.z = fmaf(__half2float(r1.h[2]), w1, a1.z);
                a1.w = fmaf(__half2float(r1.h[3]), w1, a1.w);
            }
            a0.x += a1.x; a0.y += a1.y; a0.z += a1.z; a0.w += a1.w;
            #pragma unroll
            for (int s = 8; s <= 32; s <<= 1) {
                a0.x += __shfl_xor(a0.x, s, 64);
                a0.y += __shfl_xor(a0.y, s, 64);
                a0.z += __shfl_xor(a0.z, s, 64);
                a0.w += __shfl_xor(a0.w, s, 64);
            }
            float sc = indeg_inv[node];
            float t = tanhf(a0.x * sc + b.x) * w2.x
                    + tanhf(a0.y * sc + b.y) * w2.y
                    + tanhf(a0.z * sc + b.z) * w2.z
                    + tanhf(a0.w * sc + b.w) * w2.w;
            t += __shfl_xor(t, 1, 64);
            t += __shfl_xor(t, 2, 64);
            t += __shfl_xor(t, 4, 64);
            if (lane == 0) ht2[node] = t;
        }
    }
    grid_sync(bar + 4, 1, AGG_BLOCKS);

    // ---- A3: layer-2 aggregation -> out (16 lanes per node) ----
    {
        int sub = lane >> 4;
        int slot = lane & 15;
        float bb = b2[0];
        for (int node = w * 4 + sub; node < N_NODES; node += AGG_WAVES * 4) {
            int beg = row_off[node], end = row_off[node + 1];
            float acc = 0.0f;
            for (int e = beg + slot; e < end; e += 16) {
                int2 t = ep[e];
                acc += ht2[t.x] * __int_as_float(t.y);
            }
            #pragma unroll
            for (int s = 1; s <= 8; s <<= 1) acc += __shfl_xor(acc, s, 64);
            if (slot == 0) out[node] = acc * indeg_inv[node] + bb;
        }
    }
}

extern "C" void kernel_launch(void* const* d_in, const int* in_sizes, int n_in,
                              void* d_out, int out_size, void* d_ws, size_t ws_size,
                              hipStream_t stream) {
    const float* b_z = (const float*)d_in[0];
    const int*   src = (const int*)d_in[1];
    const int*   dst = (const int*)d_in[2];
    const float* ew  = (const float*)d_in[3];
    const float* W0 = (const float*)d_in[5];
    const float* b0 = (const float*)d_in[6];
    const float* W1 = (const float*)d_in[7];
    const float* b1 = (const float*)d_in[8];
    const float* W2 = (const float*)d_in[9];
    const float* b2 = (const float*)d_in[10];
    float* out = (float*)d_out;

    const int N = N_NODES;
    const int E = N_EDGES;

    // workspace layout (16B-aligned segments); bar[16] first
    char* p = (char*)d_ws;
    int*   bar        = (int*)p;            p += 64;
    int*   row_off    = (int*)p;            p += (size_t)(N + 4) * 4;
    float* outdeg_inv = (float*)p;          p += (size_t)N * 4;
    float* indeg_inv  = (float*)p;          p += (size_t)N * 4;
    int*   histD      = (int*)p;            p += (size_t)PB * NB * 4;
    int*   histS      = (int*)p;            p += (size_t)PB * NB * 4;
    int*   offD       = (int*)p;            p += (size_t)PB * NB * 4;
    int*   offS       = (int*)p;            p += (size_t)PB * NB * 4;
    int*   coarseD    = (int*)p;            p += (size_t)(NB + 4) * 4;
    int*   coarseS    = (int*)p;            p += (size_t)(NB + 4) * 4;
    int2*  edge_perm  = (int2*)p;           p += (size_t)E * 8;
    float* bufA       = (float*)p;          p += (size_t)N * 64 * 4;
    float* bufB       = (float*)p;
    // aliases with disjoint lifetimes:
    int2*   partD = (int2*)bufA;    // dead after mega_build P5; gemm0 then writes ht into bufA
    int*    partS = (int*)bufB;     // dead after mega_build P4; mega_agg writes ht1 into bufB
    __half* ht    = (__half*)bufA;  // N x 64 fp16 (gemm0 -> A1)
    __half* ht1   = (__half*)bufB;  // N x 32 fp16 (A1 -> A2)
    float*  ht2   = bufA;           // N x 1 fp32 (A2 -> A3; ht dead by then)

    // barrier counters must start at 0 (ws is poisoned before every call)
    hipMemsetAsync(bar, 0, 64, stream);

    // CSR build (5 phases, 4 internal grid barriers)
    mega_build_kernel<<<PB, 256, 0, stream>>>(src, dst, ew, histD, histS, offD, offS,
                                              coarseD, coarseS, partD, partS,
                                              edge_perm, row_off, outdeg_inv, indeg_inv, bar);

    // layer-0 transform (must follow build: ht aliases partD)
    gemm_tile_kernel<128, 64, 4><<<N / 64, 256, 0, stream>>>(b_z, W0, ht);

    // 3 aggregation layers (2 internal grid barriers)
    mega_agg_kernel<<<AGG_BLOCKS, 256, 0, stream>>>(ht, row_off, edge_perm, indeg_inv,
                                                    b0, W1, ht1, b1, W2, ht2, b2, out, bar);
}

// Round 14
// 809.990 us; speedup vs baseline: 1.4361x; 1.4361x over previous
//
#include <hip/hip_runtime.h>
#include <hip/hip_fp16.h>
#include <math.h>

#define N_NODES 102400
#define N_EDGES 1638400
#define NB 100            // coarse buckets: node range 1024
#define PB 256            // partition blocks (= mega_build grid)
#define EPB (N_EDGES/PB)  // 6400 edges per partition block
#define AGG_BLOCKS 1536   // mega_agg grid: 6 blocks/CU on 256 CUs
#define AGG_WAVES (AGG_BLOCKS*4)

union H4 { int2 i2; __half h[4]; };

// ---- software grid barrier (all blocks resident by construction) ----
// r14 fix: RELAXED spin loads (no per-iteration cache invalidation); single release
// fence before arrive + single acquire fence after spin. r13's ACQUIRE-per-spin emitted
// buffer_inv each probe, poisoning all concurrent gathers (VALUBusy 7%, BW 370 GB/s).
__device__ __forceinline__ void grid_sync(int* bar, int idx, int nblocks) {
    __syncthreads();
    if (threadIdx.x == 0) {
        __threadfence();  // release: one-time ordering of prior writes before arrive
        __hip_atomic_fetch_add(&bar[idx], 1, __ATOMIC_RELAXED, __HIP_MEMORY_SCOPE_AGENT);
        while (__hip_atomic_load(&bar[idx], __ATOMIC_RELAXED, __HIP_MEMORY_SCOPE_AGENT) < nblocks)
            __builtin_amdgcn_s_sleep(8);
        __threadfence();  // acquire: one-time invalidate before consuming peers' data
    }
    __syncthreads();
}

// =================== mega_build: histA -> scanB -> partC -> fineS -> fineD ===================
__global__ __launch_bounds__(256) void mega_build_kernel(
    const int* __restrict__ src, const int* __restrict__ dst, const float* __restrict__ ew,
    int* __restrict__ histD, int* __restrict__ histS,
    int* __restrict__ offD, int* __restrict__ offS,
    int* __restrict__ coarseD, int* __restrict__ coarseS,
    int2* __restrict__ partD, int* __restrict__ partS,
    int2* __restrict__ edge_perm, int* __restrict__ row_off,
    float* __restrict__ outdeg_inv, float* __restrict__ indeg_inv,
    int* __restrict__ bar) {
    __shared__ int hD[NB], hS[NB];          // P1 hist / P3 cursors (reused)
    __shared__ int hist_f[1024];            // P4 src-fine hist / P5 dst-fine hist (reused)
    __shared__ int cur_f[1024];             // P5 cursors
    __shared__ int wsum[4];
    const int tid = threadIdx.x;
    const int bid = blockIdx.x;
    const int lane = tid & 63, wid = tid >> 6;

    // ---- P1: coarse histograms ----
    if (tid < NB) { hD[tid] = 0; hS[tid] = 0; }
    __syncthreads();
    {
        int base = bid * EPB;
        for (int i = tid; i < EPB; i += 256) {
            atomicAdd(&hD[dst[base + i] >> 10], 1);
            atomicAdd(&hS[src[base + i] >> 10], 1);
        }
    }
    __syncthreads();
    if (tid < NB) {
        histD[bid * NB + tid] = hD[tid];
        histS[bid * NB + tid] = hS[tid];
    }
    grid_sync(bar, 0, PB);

    // ---- P2: scan block-bucket matrices (block 0 only) ----
    if (bid == 0) {
        __shared__ int totD[NB], totS[NB], baseD[NB + 1], baseS[NB + 1];
        int t = tid;
        if (t < NB) { int s = 0; for (int k = 0; k < PB; k++) s += histD[k * NB + t]; totD[t] = s; }
        else if (t >= 128 && t < 128 + NB) { int j = t - 128; int s = 0; for (int k = 0; k < PB; k++) s += histS[k * NB + j]; totS[j] = s; }
        __syncthreads();
        if (t == 0)   { int r = 0; for (int j = 0; j < NB; j++) { baseD[j] = r; r += totD[j]; } baseD[NB] = r; }
        if (t == 128) { int r = 0; for (int j = 0; j < NB; j++) { baseS[j] = r; r += totS[j]; } baseS[NB] = r; }
        __syncthreads();
        if (t < NB) { int r = baseD[t]; for (int k = 0; k < PB; k++) { offD[k * NB + t] = r; r += histD[k * NB + t]; } }
        else if (t >= 128 && t < 128 + NB) { int j = t - 128; int r = baseS[j]; for (int k = 0; k < PB; k++) { offS[k * NB + j] = r; r += histS[k * NB + j]; } }
        if (t <= NB) coarseD[t] = baseD[t];
        if (t >= 128 && t <= 128 + NB) coarseS[t - 128] = baseS[t - 128];
    }
    grid_sync(bar, 1, PB);

    // ---- P3: partition edges into coarse buckets (LDS cursors) ----
    if (tid < NB) { hD[tid] = offD[bid * NB + tid]; hS[tid] = offS[bid * NB + tid]; }
    __syncthreads();
    {
        int base = bid * EPB;
        for (int i = tid; i < EPB; i += 256) {
            int s = src[base + i], d = dst[base + i];
            float w = ew[base + i];
            int p = atomicAdd(&hD[d >> 10], 1);
            partD[p] = make_int2(s | ((d & 1023) << 17), __float_as_int(w));
            int q = atomicAdd(&hS[s >> 10], 1);
            partS[q] = s & 1023;
        }
    }
    grid_sync(bar, 2, PB);

    // ---- P4: per src-bucket fine hist -> outdeg_inv (blocks 0..99) ----
    if (bid < NB) {
        #pragma unroll
        for (int j = 0; j < 4; ++j) hist_f[tid + j * 256] = 0;
        __syncthreads();
        int beg = coarseS[bid], end = coarseS[bid + 1];
        for (int i = beg + tid; i < end; i += 256) atomicAdd(&hist_f[partS[i]], 1);
        __syncthreads();
        int4 h = *(const int4*)&hist_f[tid * 4];
        float4 o;
        o.x = 1.0f / sqrtf((float)max(h.x, 1));
        o.y = 1.0f / sqrtf((float)max(h.y, 1));
        o.z = 1.0f / sqrtf((float)max(h.z, 1));
        o.w = 1.0f / sqrtf((float)max(h.w, 1));
        *(float4*)(outdeg_inv + bid * 1024 + tid * 4) = o;
    }
    grid_sync(bar, 3, PB);

    // ---- P5: per dst-bucket fine sort -> row_off, indeg_inv, edge_perm (blocks 0..99) ----
    if (bid < NB) {
        #pragma unroll
        for (int j = 0; j < 4; ++j) hist_f[tid + j * 256] = 0;
        __syncthreads();
        int beg = coarseD[bid], end = coarseD[bid + 1];
        for (int i = beg + tid; i < end; i += 256) atomicAdd(&hist_f[(partD[i].x >> 17) & 1023], 1);
        __syncthreads();
        int4 h = *(const int4*)&hist_f[tid * 4];
        int v = h.x + h.y + h.z + h.w;
        // block scan of per-thread totals (4 waves)
        int x = v;
        #pragma unroll
        for (int s = 1; s < 64; s <<= 1) { int t = __shfl_up(x, s, 64); if (lane >= s) x += t; }
        if (lane == 63) wsum[wid] = x;
        __syncthreads();
        if (tid == 0) { int r = 0; for (int j = 0; j < 4; ++j) { int t = wsum[j]; wsum[j] = r; r += t; } }
        __syncthreads();
        int s0 = beg + wsum[wid] + x - v;
        int s1 = s0 + h.x, s2 = s1 + h.y, s3 = s2 + h.z;
        int node = bid * 1024 + tid * 4;
        *(int4*)(row_off + node) = make_int4(s0, s1, s2, s3);
        float4 ii;
        ii.x = 1.0f / sqrtf((float)max(h.x, 1));
        ii.y = 1.0f / sqrtf((float)max(h.y, 1));
        ii.z = 1.0f / sqrtf((float)max(h.z, 1));
        ii.w = 1.0f / sqrtf((float)max(h.w, 1));
        *(float4*)(indeg_inv + node) = ii;
        *(int4*)&cur_f[tid * 4] = make_int4(s0, s1, s2, s3);
        if (bid == NB - 1 && tid == 0) row_off[N_NODES] = N_EDGES;
        __syncthreads();
        for (int i = beg + tid; i < end; i += 256) {
            int2 t2 = partD[i];
            int d = (t2.x >> 17) & 1023, s = t2.x & 0x1FFFF;
            int p = atomicAdd(&cur_f[d], 1);
            float w = __int_as_float(t2.y) * outdeg_inv[s];
            edge_perm[p] = make_int2(s, __float_as_int(w));
        }
    }
}

// =================== gemm0: out(fp16) = h @ W0, register-tiled ===================
template<int K, int C, int RN>
__global__ __launch_bounds__(256) void gemm_tile_kernel(
    const float* __restrict__ h, const float* __restrict__ W, __half* __restrict__ out) {
    constexpr int BM = 64;
    constexpr int RM = 4;
    constexpr int KC = 64;
    constexpr int TX = C / RN;
    constexpr int TY = BM / RM;
    static_assert(TX * TY == 256, "bad tile");
    static_assert(RN == 4, "fp16 epilogue assumes RN==4");

    __shared__ float Ws[K * C];
    __shared__ float Hs[KC][BM + 4];

    const int tid = threadIdx.x;
    const long brow = (long)blockIdx.x * BM;

    for (int i = tid; i < K * C; i += 256) Ws[i] = W[i];

    const int tx = tid % TX;
    const int ty = tid / TX;
    float acc[RM][RN] = {};

    const int lr = tid % 16;
    const int lk = tid / 16;

    for (int kc = 0; kc < K; kc += KC) {
        __syncthreads();
        #pragma unroll
        for (int p0 = 0; p0 < BM; p0 += 16) {
            const int r = p0 + lr;
            const float4 hv = *(const float4*)(h + (brow + r) * K + kc + lk * 4);
            Hs[lk * 4 + 0][r] = hv.x;
            Hs[lk * 4 + 1][r] = hv.y;
            Hs[lk * 4 + 2][r] = hv.z;
            Hs[lk * 4 + 3][r] = hv.w;
        }
        __syncthreads();

        #pragma unroll
        for (int k = 0; k < KC; ++k) {
            const float4 a4 = *(const float4*)&Hs[k][ty * RM];
            const float av[RM] = {a4.x, a4.y, a4.z, a4.w};
            float b[RN];
            *(float4*)b = *(const float4*)&Ws[(kc + k) * C + tx * RN];
            #pragma unroll
            for (int i = 0; i < RM; ++i)
                #pragma unroll
                for (int j = 0; j < RN; ++j)
                    acc[i][j] += av[i] * b[j];
        }
    }

    #pragma unroll
    for (int i = 0; i < RM; ++i) {
        const long row = brow + ty * RM + i;
        __half2 p01 = __floats2half2_rn(acc[i][0], acc[i][1]);
        __half2 p23 = __floats2half2_rn(acc[i][2], acc[i][3]);
        int2 packed = make_int2(*(int*)&p01, *(int*)&p23);
        *(int2*)(out + row * C + tx * RN) = packed;
    }
}

// =================== mega_agg: agg64+gemm -> agg32+dot -> agg1, persistent ===================
__global__ __launch_bounds__(256, 6) void mega_agg_kernel(
    const __half* __restrict__ ht, const int* __restrict__ row_off,
    const int2* __restrict__ ep, const float* __restrict__ indeg_inv,
    const float* __restrict__ b0, const float* __restrict__ W1,
    __half* __restrict__ ht1,
    const float* __restrict__ b1, const float* __restrict__ W2, float* __restrict__ ht2,
    const float* __restrict__ b2, float* __restrict__ out,
    int* __restrict__ bar) {
    __shared__ float W1s[64 * 32];
    __shared__ float h1s[4][64];
    const int tid = threadIdx.x;
    {   // vectorized W1 staging
        const float4* W1v = (const float4*)W1;
        float4* W1sv = (float4*)W1s;
        W1sv[tid] = W1v[tid];
        W1sv[tid + 256] = W1v[tid + 256];
    }
    __syncthreads();

    const int lane = tid & 63;
    const int wv = tid >> 6;
    const int w = blockIdx.x * 4 + wv;   // global wave id, 0..AGG_WAVES-1

    // ---- A1: layer-0 aggregation (fp16 gather) + fused 64->32 transform ----
    {
        int chunk = lane & 15;
        int eslot = lane >> 4;
        const char* htb = (const char*)ht;
        unsigned coff = (unsigned)(chunk << 3);
        int c = lane & 31, half = lane >> 5;
        for (int node = w; node < N_NODES; node += AGG_WAVES) {
            int beg = row_off[node], end = row_off[node + 1];
            float4 a0 = {0, 0, 0, 0}, a1 = {0, 0, 0, 0};
            for (int e = beg; e < end; e += 8) {
                int ei0 = e + eslot, ei1 = e + 4 + eslot;
                int2 d0 = ep[min(ei0, end - 1)];
                int2 d1 = ep[min(ei1, end - 1)];
                float w0 = (ei0 < end) ? __int_as_float(d0.y) : 0.0f;
                float w1 = (ei1 < end) ? __int_as_float(d1.y) : 0.0f;
                H4 r0, r1;
                r0.i2 = *(const int2*)(htb + (((unsigned)d0.x << 7) | coff));
                r1.i2 = *(const int2*)(htb + (((unsigned)d1.x << 7) | coff));
                a0.x = fmaf(__half2float(r0.h[0]), w0, a0.x);
                a0.y = fmaf(__half2float(r0.h[1]), w0, a0.y);
                a0.z = fmaf(__half2float(r0.h[2]), w0, a0.z);
                a0.w = fmaf(__half2float(r0.h[3]), w0, a0.w);
                a1.x = fmaf(__half2float(r1.h[0]), w1, a1.x);
                a1.y = fmaf(__half2float(r1.h[1]), w1, a1.y);
                a1.z = fmaf(__half2float(r1.h[2]), w1, a1.z);
                a1.w = fmaf(__half2float(r1.h[3]), w1, a1.w);
            }
            a0.x += a1.x; a0.y += a1.y; a0.z += a1.z; a0.w += a1.w;
            #pragma unroll
            for (int s = 16; s <= 32; s <<= 1) {
                a0.x += __shfl_xor(a0.x, s, 64);
                a0.y += __shfl_xor(a0.y, s, 64);
                a0.z += __shfl_xor(a0.z, s, 64);
                a0.w += __shfl_xor(a0.w, s, 64);
            }
            if (eslot == 0) {
                float sc = indeg_inv[node];
                float4 b = *(const float4*)(b0 + chunk * 4);
                float4 v;
                v.x = tanhf(a0.x * sc + b.x);
                v.y = tanhf(a0.y * sc + b.y);
                v.z = tanhf(a0.z * sc + b.z);
                v.w = tanhf(a0.w * sc + b.w);
                *(float4*)&h1s[wv][chunk * 4] = v;
            }
            float t = 0.0f;
            #pragma unroll
            for (int j4 = 0; j4 < 8; ++j4) {
                int k = half * 32 + j4 * 4;
                float4 hh = *(const float4*)&h1s[wv][k];
                t += hh.x * W1s[(k + 0) * 32 + c];
                t += hh.y * W1s[(k + 1) * 32 + c];
                t += hh.z * W1s[(k + 2) * 32 + c];
                t += hh.w * W1s[(k + 3) * 32 + c];
            }
            t += __shfl_xor(t, 32, 64);
            if (half == 0) ht1[(long)node * 32 + c] = __float2half_rn(t);
        }
    }
    grid_sync(bar + 4, 0, AGG_BLOCKS);

    // ---- A2: layer-1 aggregation (fp16 gather) + fused 32->1 dot ----
    {
        int chunk = lane & 7;
        int eslot = lane >> 3;
        const char* htb = (const char*)ht1;
        unsigned coff = (unsigned)(chunk << 3);
        float4 b = *(const float4*)(b1 + chunk * 4);
        float4 w2 = *(const float4*)(W2 + chunk * 4);
        for (int node = w; node < N_NODES; node += AGG_WAVES) {
            int beg = row_off[node], end = row_off[node + 1];
            float4 a0 = {0, 0, 0, 0}, a1 = {0, 0, 0, 0};
            for (int e = beg; e < end; e += 16) {
                int ei0 = e + eslot, ei1 = e + 8 + eslot;
                int2 d0 = ep[min(ei0, end - 1)];
                int2 d1 = ep[min(ei1, end - 1)];
                float w0 = (ei0 < end) ? __int_as_float(d0.y) : 0.0f;
                float w1 = (ei1 < end) ? __int_as_float(d1.y) : 0.0f;
                H4 r0, r1;
                r0.i2 = *(const int2*)(htb + (((unsigned)d0.x << 6) | coff));
                r1.i2 = *(const int2*)(htb + (((unsigned)d1.x << 6) | coff));
                a0.x = fmaf(__half2float(r0.h[0]), w0, a0.x);
                a0.y = fmaf(__half2float(r0.h[1]), w0, a0.y);
                a0.z = fmaf(__half2float(r0.h[2]), w0, a0.z);
                a0.w = fmaf(__half2float(r0.h[3]), w0, a0.w);
                a1.x = fmaf(__half2float(r1.h[0]), w1, a1.x);
                a1.y = fmaf(__half2float(r1.h[1]), w1, a1.y);
                a1.z = fmaf(__half2float(r1.h[2]), w1, a1.z);
                a1.w = fmaf(__half2float(r1.h[3]), w1, a1.w);
            }
            a0.x += a1.x; a0.y += a1.y; a0.z += a1.z; a0.w += a1.w;
            #pragma unroll
            for (int s = 8; s <= 32; s <<= 1) {
                a0.x += __shfl_xor(a0.x, s, 64);
                a0.y += __shfl_xor(a0.y, s, 64);
                a0.z += __shfl_xor(a0.z, s, 64);
                a0.w += __shfl_xor(a0.w, s, 64);
            }
            float sc = indeg_inv[node];
            float t = tanhf(a0.x * sc + b.x) * w2.x
                    + tanhf(a0.y * sc + b.y) * w2.y
                    + tanhf(a0.z * sc + b.z) * w2.z
                    + tanhf(a0.w * sc + b.w) * w2.w;
            t += __shfl_xor(t, 1, 64);
            t += __shfl_xor(t, 2, 64);
            t += __shfl_xor(t, 4, 64);
            if (lane == 0) ht2[node] = t;
        }
    }
    grid_sync(bar + 4, 1, AGG_BLOCKS);

    // ---- A3: layer-2 aggregation -> out (16 lanes per node) ----
    {
        int sub = lane >> 4;
        int slot = lane & 15;
        float bb = b2[0];
        for (int node = w * 4 + sub; node < N_NODES; node += AGG_WAVES * 4) {
            int beg = row_off[node], end = row_off[node + 1];
            float acc = 0.0f;
            for (int e = beg + slot; e < end; e += 16) {
                int2 t = ep[e];
                acc += ht2[t.x] * __int_as_float(t.y);
            }
            #pragma unroll
            for (int s = 1; s <= 8; s <<= 1) acc += __shfl_xor(acc, s, 64);
            if (slot == 0) out[node] = acc * indeg_inv[node] + bb;
        }
    }
}

extern "C" void kernel_launch(void* const* d_in, const int* in_sizes, int n_in,
                              void* d_out, int out_size, void* d_ws, size_t ws_size,
                              hipStream_t stream) {
    const float* b_z = (const float*)d_in[0];
    const int*   src = (const int*)d_in[1];
    const int*   dst = (const int*)d_in[2];
    const float* ew  = (const float*)d_in[3];
    const float* W0 = (const float*)d_in[5];
    const float* b0 = (const float*)d_in[6];
    const float* W1 = (const float*)d_in[7];
    const float* b1 = (const float*)d_in[8];
    const float* W2 = (const float*)d_in[9];
    const float* b2 = (const float*)d_in[10];
    float* out = (float*)d_out;

    const int N = N_NODES;
    const int E = N_EDGES;

    // workspace layout (16B-aligned segments); bar[16] first
    char* p = (char*)d_ws;
    int*   bar        = (int*)p;            p += 64;
    int*   row_off    = (int*)p;            p += (size_t)(N + 4) * 4;
    float* outdeg_inv = (float*)p;          p += (size_t)N * 4;
    float* indeg_inv  = (float*)p;          p += (size_t)N * 4;
    int*   histD      = (int*)p;            p += (size_t)PB * NB * 4;
    int*   histS      = (int*)p;            p += (size_t)PB * NB * 4;
    int*   offD       = (int*)p;            p += (size_t)PB * NB * 4;
    int*   offS       = (int*)p;            p += (size_t)PB * NB * 4;
    int*   coarseD    = (int*)p;            p += (size_t)(NB + 4) * 4;
    int*   coarseS    = (int*)p;            p += (size_t)(NB + 4) * 4;
    int2*  edge_perm  = (int2*)p;           p += (size_t)E * 8;
    float* bufA       = (float*)p;          p += (size_t)N * 64 * 4;
    float* bufB       = (float*)p;
    // aliases with disjoint lifetimes:
    int2*   partD = (int2*)bufA;    // dead after mega_build P5; gemm0 then writes ht into bufA
    int*    partS = (int*)bufB;     // dead after mega_build P4; mega_agg writes ht1 into bufB
    __half* ht    = (__half*)bufA;  // N x 64 fp16 (gemm0 -> A1)
    __half* ht1   = (__half*)bufB;  // N x 32 fp16 (A1 -> A2)
    float*  ht2   = bufA;           // N x 1 fp32 (A2 -> A3; ht dead by then)

    // barrier counters must start at 0 (ws is poisoned before every call)
    hipMemsetAsync(bar, 0, 64, stream);

    // CSR build (5 phases, 4 internal grid barriers)
    mega_build_kernel<<<PB, 256, 0, stream>>>(src, dst, ew, histD, histS, offD, offS,
                                              coarseD, coarseS, partD, partS,
                                              edge_perm, row_off, outdeg_inv, indeg_inv, bar);

    // layer-0 transform (must follow build: ht aliases partD)
    gemm_tile_kernel<128, 64, 4><<<N / 64, 256, 0, stream>>>(b_z, W0, ht);

    // 3 aggregation layers (2 internal grid barriers)
    mega_agg_kernel<<<AGG_BLOCKS, 256, 0, stream>>>(ht, row_off, edge_perm, indeg_inv,
                                                    b0, W1, ht1, b1, W2, ht2, b2, out, bar);
}